// Round 3
// baseline (28.175 us; speedup 1.0000x reference)
//
#include <hip/hip_runtime.h>
#include <math.h>

#define FDIM 14
#define HBINS 7
#define WBINS 7
#define CELLS_N (HBINS * WBINS)     // 49
#define NBLOCKS 2048
#define NTHREADS 256

typedef float floatx4 __attribute__((ext_vector_type(4)));  // native vec: OK for nontemporal builtins

// Persistent grid-stride kernel. Work item = one float4 channel-chunk of one
// output cell: chunk = cell*128 + t, cell = n*49 + bh*7 + bw, t in [0,128).
// Consecutive threads -> consecutive chunks -> perfectly coalesced stores.
__global__ __launch_bounds__(NTHREADS) void roi_pool_kernel(
    const float* __restrict__ fm,    // [F, F, C]
    const float* __restrict__ rois,  // [N, 4]
    float* __restrict__ out,         // [N, H, W, C]
    int total_chunks,                // N * 49 * (C/4)
    int C4)                          // C/4
{
    const floatx4* fm4  = (const floatx4*)fm;
    floatx4*       out4 = (floatx4*)out;
    const floatx4* roi4 = (const floatx4*)rois;

    for (int idx = blockIdx.x * NTHREADS + threadIdx.x;
         idx < total_chunks;
         idx += NBLOCKS * NTHREADS) {

        const int t    = idx & 127;          // channel chunk (C4 == 128)
        const int cell = idx >> 7;
        const int n    = cell / CELLS_N;
        const int rem  = cell - n * CELLS_N;
        const int bh   = rem / WBINS;
        const int bw   = rem - bh * WBINS;

        // ROI params (uniform across the 128 threads sharing a cell; L1-broadcast)
        const floatx4 r = roi4[n];
        const int x_min = (int)floorf((float)FDIM * r.x);
        const int y_min = (int)floorf((float)FDIM * r.y);
        const int x_max = (int)floorf((float)FDIM * r.z);
        const int y_max = (int)floorf((float)FDIM * r.w);
        const int rw = x_max - x_min;
        const int rh = y_max - y_min;
        const int sw = rw / WBINS;
        const int sh = rh / HBINS;

        // TF binning: bin bh covers rows [bh*sh, (bh+1)*sh) for bh<6,
        // [6*sh, rh) for bh==6; sh==0 dumps all rows into bin 6.
        int r0, r1, c0, c1;
        if (sh > 0) { r0 = bh * sh; r1 = (bh < HBINS - 1) ? (bh + 1) * sh : rh; }
        else        { r0 = 0;       r1 = (bh == HBINS - 1) ? rh : 0; }
        if (sw > 0) { c0 = bw * sw; c1 = (bw < WBINS - 1) ? (bw + 1) * sw : rw; }
        else        { c0 = 0;       c1 = (bw == WBINS - 1) ? rw : 0; }

        // Clip to feature-map grid
        r0 = max(r0, -y_min);  r1 = min(r1, FDIM - y_min);
        c0 = max(c0, -x_min);  c1 = min(c1, FDIM - x_min);

        floatx4 acc = { -INFINITY, -INFINITY, -INFINITY, -INFINITY };

        for (int ry = r0; ry < r1; ++ry) {
            const int ys = y_min + ry;
            const floatx4* row = fm4 + (size_t)(ys * FDIM) * C4;
            for (int rx = c0; rx < c1; ++rx) {
                const int xs = x_min + rx;
                const floatx4 v = row[(size_t)xs * C4 + t];
                acc.x = fmaxf(acc.x, v.x);
                acc.y = fmaxf(acc.y, v.y);
                acc.z = fmaxf(acc.z, v.z);
                acc.w = fmaxf(acc.w, v.w);
            }
        }

        // Output written once, never re-read: bypass L2 so fm stays resident.
        __builtin_nontemporal_store(acc, &out4[idx]);
    }
}

extern "C" void kernel_launch(void* const* d_in, const int* in_sizes, int n_in,
                              void* d_out, int out_size, void* d_ws, size_t ws_size,
                              hipStream_t stream) {
    const float* fm   = (const float*)d_in[0];   // [1, 14, 14, C]
    const float* rois = (const float*)d_in[1];   // [1, N, 4]

    const int C  = in_sizes[0] / (FDIM * FDIM);  // 512
    const int N  = in_sizes[1] / 4;              // 1024
    const int C4 = C / 4;                        // 128

    float* out = (float*)d_out;                  // [N, 7, 7, C]
    const int total_chunks = N * CELLS_N * C4;   // 6,422,528

    roi_pool_kernel<<<NBLOCKS, NTHREADS, 0, stream>>>(fm, rois, out, total_chunks, C4);
}

// Round 4
// 22.408 us; speedup vs baseline: 1.2574x; 1.2574x over previous
//
#include <hip/hip_runtime.h>
#include <math.h>

#define FDIM 14
#define HBINS 7
#define WBINS 7
#define NTHREADS 448   // 7 waves: wave w handles bin column bw=w; lane owns 2 float4 chunks

typedef float floatx4 __attribute__((ext_vector_type(4)));

// One block per (roi n, bin row bh). Wave w = bin column bw. C=512 -> C4=128
// float4 chunks per cell; lane owns chunks {lane, lane+64}. All ROI math is
// blockIdx-derived (scalar) except c0/c1 (wave-uniform). Stores are normal
// (cached) 16B per lane, 1KB contiguous per wave instruction.
__global__ __launch_bounds__(NTHREADS) void roi_pool_kernel(
    const float* __restrict__ fm,    // [14, 14, 512]
    const float* __restrict__ rois,  // [N, 4]
    float* __restrict__ out)         // [N, 7, 7, 512]
{
    const int nb = blockIdx.x;
    const int n  = nb / HBINS;
    const int bh = nb - n * HBINS;

    const floatx4* fm4  = (const floatx4*)fm;
    floatx4*       out4 = (floatx4*)out;

    // ROI decode — blockIdx-derived, compiler scalarizes (s_load + SALU).
    const floatx4 r = ((const floatx4*)rois)[n];
    const int x_min = (int)floorf((float)FDIM * r.x);
    const int y_min = (int)floorf((float)FDIM * r.y);
    const int x_max = (int)floorf((float)FDIM * r.z);
    const int y_max = (int)floorf((float)FDIM * r.w);
    const int rw = x_max - x_min;
    const int rh = y_max - y_min;
    const int sw = rw / WBINS;
    const int sh = rh / HBINS;

    // Row range for this bh (TF binning; sh==0 dumps all rows into bin 6).
    int r0, r1;
    if (sh > 0) { r0 = bh * sh; r1 = (bh < HBINS - 1) ? (bh + 1) * sh : rh; }
    else        { r0 = 0;       r1 = (bh == HBINS - 1) ? rh : 0; }
    r0 = max(r0, -y_min);  r1 = min(r1, FDIM - y_min);

    // Column range for this wave's bw (wave-uniform).
    const int bw   = threadIdx.x >> 6;   // 0..6
    const int lane = threadIdx.x & 63;
    int c0, c1;
    if (sw > 0) { c0 = bw * sw; c1 = (bw < WBINS - 1) ? (bw + 1) * sw : rw; }
    else        { c0 = 0;       c1 = (bw == WBINS - 1) ? rw : 0; }
    c0 = max(c0, -x_min);  c1 = min(c1, FDIM - x_min);

    floatx4 acc0 = { -INFINITY, -INFINITY, -INFINITY, -INFINITY };
    floatx4 acc1 = acc0;

    for (int ry = r0; ry < r1; ++ry) {
        const int ys = y_min + ry;
        const floatx4* row = fm4 + (size_t)(ys * FDIM) * 128;
        for (int rx = c0; rx < c1; ++rx) {
            const floatx4* px = row + (size_t)(x_min + rx) * 128;
            const floatx4 v0 = px[lane];
            const floatx4 v1 = px[lane + 64];
            acc0.x = fmaxf(acc0.x, v0.x);  acc0.y = fmaxf(acc0.y, v0.y);
            acc0.z = fmaxf(acc0.z, v0.z);  acc0.w = fmaxf(acc0.w, v0.w);
            acc1.x = fmaxf(acc1.x, v1.x);  acc1.y = fmaxf(acc1.y, v1.y);
            acc1.z = fmaxf(acc1.z, v1.z);  acc1.w = fmaxf(acc1.w, v1.w);
        }
    }

    const size_t cellbase = (size_t)((n * (HBINS * WBINS) + bh * WBINS + bw)) * 128;
    out4[cellbase + lane]      = acc0;
    out4[cellbase + lane + 64] = acc1;
}

extern "C" void kernel_launch(void* const* d_in, const int* in_sizes, int n_in,
                              void* d_out, int out_size, void* d_ws, size_t ws_size,
                              hipStream_t stream) {
    const float* fm   = (const float*)d_in[0];   // [1, 14, 14, 512]
    const float* rois = (const float*)d_in[1];   // [1, N, 4]
    const int N = in_sizes[1] / 4;               // 1024

    float* out = (float*)d_out;                  // [N, 7, 7, 512]

    const int blocks = N * HBINS;                // 7168
    roi_pool_kernel<<<blocks, NTHREADS, 0, stream>>>(fm, rois, out);
}